// Round 2
// baseline (279.810 us; speedup 1.0000x reference)
//
#include <hip/hip_runtime.h>
#include <hip/hip_fp16.h>

// ---------------------------------------------------------------------------
// GCN forward: h1 = relu(GCNConv(x, W1, b1)); h2 = relu(GCNConv(h1, W2, b2));
// out = h2 @ W_lin + b_lin
// N=100000, E=3200000, F_in=128, H=16, F_out=128.
// edge_index arrives as int32 [2*E]: row 0 = src, row 1 = dst.
//
// R10 pipeline (memset + 7 kernels):
//   memset(bucket_cnt) -> bucket_cnt -> scan -> partition (packed pairs,
//   bucket-contiguous) -> sortd (per-bucket counting sort by dst-local:
//   srcs[] fully dst-sorted + nodeoff/deg/dinv; replaces k_deg)
//   -> xform1 -> aggr1r -> aggr2r.
// R10 change: R8/R9 post-mortem showed LDS-atomic scatter structure is the
// wall (time invariant to VALU count & load width; 16 atomics/edge RMW
// rounds + 391-block imbalance). Aggregation is now CSR register-space
// reduction: 16 lanes/node (8 edge-slots x 2 half-rows), fp32 accumulate
// in VGPRs, 3-step shfl_xor butterfly. ZERO accumulator atomics, no
// fixed point needed (fixed reduction order = deterministic). Sort costs
// 1 LDS atomic/edge (16x fewer than aggregation did).
// ---------------------------------------------------------------------------

typedef int   v4i __attribute__((ext_vector_type(4)));
typedef float v4f __attribute__((ext_vector_type(4)));
typedef float v2f __attribute__((ext_vector_type(2)));

#define NPB        256    // nodes per bucket
#define NPB_SHIFT  8
#define NB_MAX     512    // max buckets
#define PART_TILE  8192   // edges per partition block
#define PART_THR   1024
#define PT_ITERS   (PART_TILE / 4 / PART_THR)   // = 2 quads/thread

// Per-block LDS histogram of dst>>8, int4 loads, flushed once per block.
__global__ __launch_bounds__(256) void k_bucket_cnt(const int* __restrict__ ei,
                                                    int* __restrict__ bucket_cnt, int E) {
    __shared__ int h[NB_MAX];
    int t = threadIdx.x;
    for (int j = t; j < NB_MAX; j += 256) h[j] = 0;
    __syncthreads();
    const v4i* d4 = (const v4i*)(ei + E);
    int EQ = E >> 2;
    for (int q = blockIdx.x * 256 + t; q < EQ; q += gridDim.x * 256) {
        v4i dd = __builtin_nontemporal_load(d4 + q);
        atomicAdd(&h[dd.x >> NPB_SHIFT], 1);
        atomicAdd(&h[dd.y >> NPB_SHIFT], 1);
        atomicAdd(&h[dd.z >> NPB_SHIFT], 1);
        atomicAdd(&h[dd.w >> NPB_SHIFT], 1);
    }
    if (blockIdx.x == 0) {
        for (int e = (EQ << 2) + t; e < E; e += 256)
            atomicAdd(&h[ei[E + e] >> NPB_SHIFT], 1);
    }
    __syncthreads();
    for (int j = t; j < NB_MAX; j += 256)
        if (h[j]) atomicAdd(&bucket_cnt[j], h[j]);
}

// Exclusive scan of padded counts (pad to 16 pairs: 64B-aligned regions).
__global__ __launch_bounds__(NB_MAX) void k_bucket_scan(const int* __restrict__ bucket_cnt,
                                                        int* __restrict__ bucket_base,
                                                        int* __restrict__ bucket_cur) {
    __shared__ int s[NB_MAX];
    int t = threadIdx.x;
    int padded = (bucket_cnt[t] + 15) & ~15;
    s[t] = padded;
    __syncthreads();
    for (int off = 1; off < NB_MAX; off <<= 1) {
        int v = (t >= off) ? s[t - off] : 0;
        __syncthreads();
        s[t] += v;
        __syncthreads();
    }
    int excl = s[t] - padded;
    bucket_base[t] = excl;
    bucket_cur[t]  = excl;
}

// Partition edges into bucket-contiguous packed (src<<8 | dstlocal) runs.
__global__ __launch_bounds__(PART_THR) void k_partition(const int* __restrict__ ei,
                                                        int* __restrict__ bucket_cur,
                                                        int* __restrict__ pairs, int E) {
    __shared__ int h[NB_MAX];    // pass1: local hist; pass2: local cursor
    __shared__ int rb[NB_MAX];   // run base (absolute) per bucket
    int t = threadIdx.x;
    const v4i* s4 = (const v4i*)ei;
    const v4i* d4 = (const v4i*)(ei + E);
    int EQ = E >> 2;
    int q0 = blockIdx.x * (PART_TILE / 4);
    bool last = (blockIdx.x == gridDim.x - 1);
    v4i dsave[PT_ITERS];

    for (int j = t; j < NB_MAX; j += PART_THR) h[j] = 0;
    __syncthreads();
#pragma unroll
    for (int it = 0; it < PT_ITERS; ++it) {
        int q = q0 + it * PART_THR + t;
        v4i dd;
        if (q < EQ) {
            dd = __builtin_nontemporal_load(d4 + q);
            atomicAdd(&h[dd.x >> NPB_SHIFT], 1);
            atomicAdd(&h[dd.y >> NPB_SHIFT], 1);
            atomicAdd(&h[dd.z >> NPB_SHIFT], 1);
            atomicAdd(&h[dd.w >> NPB_SHIFT], 1);
        }
        dsave[it] = dd;
    }
    if (last) {
        for (int e = (EQ << 2) + t; e < E; e += PART_THR)
            atomicAdd(&h[ei[E + e] >> NPB_SHIFT], 1);
    }
    __syncthreads();
    for (int j = t; j < NB_MAX; j += PART_THR) {
        int c = h[j];
        rb[j] = c ? atomicAdd(&bucket_cur[j], c) : 0;
        h[j] = 0;
    }
    __syncthreads();
#pragma unroll
    for (int it = 0; it < PT_ITERS; ++it) {
        int q = q0 + it * PART_THR + t;
        if (q < EQ) {
            v4i ss = __builtin_nontemporal_load(s4 + q);
            v4i dd = dsave[it];
#pragma unroll
            for (int k = 0; k < 4; ++k) {
                int s = ss[k], d = dd[k];
                int b = d >> NPB_SHIFT;
                int pos = rb[b] + atomicAdd(&h[b], 1);
                pairs[pos] = (s << NPB_SHIFT) | (d & (NPB - 1));
            }
        }
    }
    if (last) {
        for (int e = (EQ << 2) + t; e < E; e += PART_THR) {
            int s = ei[e], d = ei[E + e];
            int b = d >> NPB_SHIFT;
            int pos = rb[b] + atomicAdd(&h[b], 1);
            pairs[pos] = (s << NPB_SHIFT) | (d & (NPB - 1));
        }
    }
}

// Per-bucket counting sort by dst-local. Produces srcs[] (src ids grouped by
// dst, dense in [base, base+cnt)), nodeoff[n], degarr[n], dinv[n].
// 1 LDS atomic per edge (hist) + 1 (cursor) vs 16/edge in old aggregation.
__global__ __launch_bounds__(1024) void k_sortd(const int* __restrict__ pairs,
                                                const int* __restrict__ bucket_cnt,
                                                const int* __restrict__ bucket_base,
                                                int* __restrict__ srcs,
                                                int* __restrict__ nodeoff,
                                                int* __restrict__ degarr,
                                                float* __restrict__ dinv, int N) {
    __shared__ int h[NPB];    // hist -> inclusive scan (in place)
    __shared__ int cur[NPB];  // scatter cursors (absolute)
    int t = threadIdx.x, b = blockIdx.x;
    int cnt  = bucket_cnt[b];
    int base = bucket_base[b];   // 16-aligned
    if (t < NPB) h[t] = 0;
    __syncthreads();
    const v4i* p4 = (const v4i*)(pairs + base);
    int cq = cnt >> 2;
    for (int q = t; q < cq; q += 1024) {
        v4i pp = p4[q];
        atomicAdd(&h[pp.x & (NPB - 1)], 1);
        atomicAdd(&h[pp.y & (NPB - 1)], 1);
        atomicAdd(&h[pp.z & (NPB - 1)], 1);
        atomicAdd(&h[pp.w & (NPB - 1)], 1);
    }
    for (int i = (cq << 2) + t; i < cnt; i += 1024)
        atomicAdd(&h[pairs[base + i] & (NPB - 1)], 1);
    __syncthreads();
    int mydeg = (t < NPB) ? h[t] : 0;
    // Hillis-Steele inclusive scan over h[0..255]
    for (int off = 1; off < NPB; off <<= 1) {
        int v = (t < NPB && t >= off) ? h[t - off] : 0;
        __syncthreads();
        if (t < NPB) h[t] += v;
        __syncthreads();
    }
    if (t < NPB) {
        int no = base + h[t] - mydeg;   // exclusive
        cur[t] = no;
        int n = (b << NPB_SHIFT) + t;
        if (n < N) {
            nodeoff[n] = no;
            degarr[n]  = mydeg;
            dinv[n]    = rsqrtf((float)(mydeg + 1));
        }
    }
    __syncthreads();
    for (int q = t; q < cq; q += 1024) {
        v4i pp = p4[q];
#pragma unroll
        for (int k = 0; k < 4; ++k) {
            int p = pp[k];
            int pos = atomicAdd(&cur[p & (NPB - 1)], 1);
            srcs[pos] = p >> NPB_SHIFT;
        }
    }
    for (int i = (cq << 2) + t; i < cnt; i += 1024) {
        int p = pairs[base + i];
        int pos = atomicAdd(&cur[p & (NPB - 1)], 1);
        srcs[pos] = p >> NPB_SHIFT;
    }
}

// g1[n,:] = fp16( (x[n,:] @ W1) * dinv[n] )   (128 -> 16), 16 nodes per block
__global__ __launch_bounds__(256) void k_xform1(const float* __restrict__ x,
                                                const float* __restrict__ W1,
                                                const float* __restrict__ dinv,
                                                __half* __restrict__ g, int N) {
    __shared__ float xs[16][132];
    __shared__ float ws[128 * 16];
    int t = threadIdx.x;
    int n0 = blockIdx.x * 16;
    const v4f* w4 = (const v4f*)W1;
    const v4f* x4 = (const v4f*)x;
    for (int idx = t; idx < 512; idx += 256) ((v4f*)ws)[idx] = w4[idx];
    for (int idx = t; idx < 512; idx += 256) {
        int r = idx >> 5, c4 = idx & 31;
        int n = n0 + r;
        v4f v = (n < N) ? x4[(size_t)n * 32 + c4] : (v4f)(0.f);
        *(v4f*)&xs[r][c4 * 4] = v;
    }
    __syncthreads();
    int node = t >> 4, f = t & 15;
    int n = n0 + node;
    if (n < N) {
        float sum = 0.f;
#pragma unroll
        for (int k = 0; k < 128; ++k) sum += xs[node][k] * ws[k * 16 + f];
        g[(size_t)n * 16 + f] = __float2half_rn(sum * dinv[n]);
    }
}

// ---- R10 register-reduction aggregation -----------------------------------
// Block = 256-node range, 16 waves. Wave handles 16 nodes (4 groups of 4).
// Per node: 16 lanes = 8 edge-slots x 2 half-rows (8 fp16 feats each).
// fp32 accumulate in VGPRs over CSR range; shfl_xor butterfly (masks 2,4,8);
// lanes es==0 fuse self+bias+relu and write h (fp32) to LDS; phase B does
// the bucket-level GEMM epilogue. No accumulator atomics anywhere.

// Layer-1: g2[n,:] = fp16( relu(dinv*(sum+self)+b1) @ W2 * dinv )
__global__ __launch_bounds__(1024) void k_aggr1r(const __half* __restrict__ g1,
                                                 const int* __restrict__ srcs,
                                                 const int* __restrict__ nodeoff,
                                                 const int* __restrict__ degarr,
                                                 const float* __restrict__ dinv,
                                                 const float* __restrict__ b1,
                                                 const float* __restrict__ W2,
                                                 __half* __restrict__ g2, int N) {
    __shared__ float accf[NPB * 20];    // stride 20: b128-aligned, bank-clean
    __shared__ float w2s[256];
    __shared__ float b1s[16];
    int t = threadIdx.x, b = blockIdx.x;
    int n0 = b << NPB_SHIFT;
    if (t < 256) w2s[t] = W2[t];
    if (t < 16)  b1s[t] = b1[t];
    __syncthreads();
    int w = t >> 6, l = t & 63;
    int sub = l >> 4, es = (l >> 1) & 7, fo = (l & 1) << 3;
#pragma unroll
    for (int g = 0; g < 4; ++g) {
        int nl = w * 16 + g * 4 + sub;
        int n = n0 + nl;
        float fa[8] = {0.f, 0.f, 0.f, 0.f, 0.f, 0.f, 0.f, 0.f};
        if (n < N) {
            int off = nodeoff[n], deg = degarr[n];
            for (int c = es; c < deg; c += 8) {
                int s = srcs[off + c];
                v4i r = *(const v4i*)(g1 + (size_t)s * 16 + fo);
#pragma unroll
                for (int j = 0; j < 4; ++j) {
                    float2 fv = __half22float2(((const __half2*)&r)[j]);
                    fa[2 * j]     += fv.x;
                    fa[2 * j + 1] += fv.y;
                }
            }
        }
#pragma unroll
        for (int m = 2; m <= 8; m <<= 1) {
#pragma unroll
            for (int j = 0; j < 8; ++j) fa[j] += __shfl_xor(fa[j], m, 64);
        }
        if (es == 0 && n < N) {
            v4i sr = *(const v4i*)(g1 + (size_t)n * 16 + fo);
            float di = dinv[n];
            float h0, h1v, h2, h3, h4, h5, h6, h7;
            float2 s0 = __half22float2(((const __half2*)&sr)[0]);
            float2 s1 = __half22float2(((const __half2*)&sr)[1]);
            float2 s2 = __half22float2(((const __half2*)&sr)[2]);
            float2 s3 = __half22float2(((const __half2*)&sr)[3]);
            h0 = fmaxf(di * (fa[0] + s0.x) + b1s[fo + 0], 0.f);
            h1v= fmaxf(di * (fa[1] + s0.y) + b1s[fo + 1], 0.f);
            h2 = fmaxf(di * (fa[2] + s1.x) + b1s[fo + 2], 0.f);
            h3 = fmaxf(di * (fa[3] + s1.y) + b1s[fo + 3], 0.f);
            h4 = fmaxf(di * (fa[4] + s2.x) + b1s[fo + 4], 0.f);
            h5 = fmaxf(di * (fa[5] + s2.y) + b1s[fo + 5], 0.f);
            h6 = fmaxf(di * (fa[6] + s3.x) + b1s[fo + 6], 0.f);
            h7 = fmaxf(di * (fa[7] + s3.y) + b1s[fo + 7], 0.f);
            v4f lo = {h0, h1v, h2, h3};
            v4f hi = {h4, h5, h6, h7};
            *((v4f*)(accf + nl * 20 + fo))     = lo;
            *((v4f*)(accf + nl * 20 + fo + 4)) = hi;
        }
    }
    __syncthreads();
    // phase B: g2 = fp16((h1 @ W2) * dinv), 2048 half2 outputs
#pragma unroll
    for (int r = 0; r < 2; ++r) {
        int idx2 = r * 1024 + t;         // 2048 = 256*8
        int d = idx2 >> 3, ff = idx2 & 7;
        int n = n0 + d;
        if (n < N) {
            float sx = 0.f, sy = 0.f;
#pragma unroll
            for (int k = 0; k < 16; ++k) {
                float hv = accf[d * 20 + k];
                sx += hv * w2s[k * 16 + 2 * ff];
                sy += hv * w2s[k * 16 + 2 * ff + 1];
            }
            float di = dinv[n];
            *(__half2*)(g2 + (size_t)n * 16 + 2 * ff) = __floats2half2_rn(sx * di, sy * di);
        }
    }
}

// Layer-2: out[n,:] = relu(dinv*(sum+self)+b2) @ W_lin + b_lin
__global__ __launch_bounds__(1024) void k_aggr2r(const __half* __restrict__ g2,
                                                 const int* __restrict__ srcs,
                                                 const int* __restrict__ nodeoff,
                                                 const int* __restrict__ degarr,
                                                 const float* __restrict__ dinv,
                                                 const float* __restrict__ b2,
                                                 const float* __restrict__ Wl,
                                                 const float* __restrict__ bl,
                                                 float* __restrict__ out, int N) {
    __shared__ float accf[NPB * 20];
    __shared__ float wls[16 * 128];
    __shared__ float bls[128];
    __shared__ float b2s[16];
    int t = threadIdx.x, b = blockIdx.x;
    int n0 = b << NPB_SHIFT;
    if (t < 512) ((v4f*)wls)[t] = ((const v4f*)Wl)[t];
    if (t < 128) bls[t] = bl[t];
    if (t < 16)  b2s[t] = b2[t];
    __syncthreads();
    int w = t >> 6, l = t & 63;
    int sub = l >> 4, es = (l >> 1) & 7, fo = (l & 1) << 3;
#pragma unroll
    for (int g = 0; g < 4; ++g) {
        int nl = w * 16 + g * 4 + sub;
        int n = n0 + nl;
        float fa[8] = {0.f, 0.f, 0.f, 0.f, 0.f, 0.f, 0.f, 0.f};
        if (n < N) {
            int off = nodeoff[n], deg = degarr[n];
            for (int c = es; c < deg; c += 8) {
                int s = srcs[off + c];
                v4i r = *(const v4i*)(g2 + (size_t)s * 16 + fo);
#pragma unroll
                for (int j = 0; j < 4; ++j) {
                    float2 fv = __half22float2(((const __half2*)&r)[j]);
                    fa[2 * j]     += fv.x;
                    fa[2 * j + 1] += fv.y;
                }
            }
        }
#pragma unroll
        for (int m = 2; m <= 8; m <<= 1) {
#pragma unroll
            for (int j = 0; j < 8; ++j) fa[j] += __shfl_xor(fa[j], m, 64);
        }
        if (es == 0 && n < N) {
            v4i sr = *(const v4i*)(g2 + (size_t)n * 16 + fo);
            float di = dinv[n];
            float2 s0 = __half22float2(((const __half2*)&sr)[0]);
            float2 s1 = __half22float2(((const __half2*)&sr)[1]);
            float2 s2 = __half22float2(((const __half2*)&sr)[2]);
            float2 s3 = __half22float2(((const __half2*)&sr)[3]);
            float h0 = fmaxf(di * (fa[0] + s0.x) + b2s[fo + 0], 0.f);
            float h1v= fmaxf(di * (fa[1] + s0.y) + b2s[fo + 1], 0.f);
            float h2 = fmaxf(di * (fa[2] + s1.x) + b2s[fo + 2], 0.f);
            float h3 = fmaxf(di * (fa[3] + s1.y) + b2s[fo + 3], 0.f);
            float h4 = fmaxf(di * (fa[4] + s2.x) + b2s[fo + 4], 0.f);
            float h5 = fmaxf(di * (fa[5] + s2.y) + b2s[fo + 5], 0.f);
            float h6 = fmaxf(di * (fa[6] + s3.x) + b2s[fo + 6], 0.f);
            float h7 = fmaxf(di * (fa[7] + s3.y) + b2s[fo + 7], 0.f);
            v4f lo = {h0, h1v, h2, h3};
            v4f hi = {h4, h5, h6, h7};
            *((v4f*)(accf + nl * 20 + fo))     = lo;
            *((v4f*)(accf + nl * 20 + fo + 4)) = hi;
        }
    }
    __syncthreads();
    // phase B: out = h2 @ W_lin + b_lin; 16384 float2 outputs, coalesced
    const v2f* wl2 = (const v2f*)wls;
#pragma unroll
    for (int r = 0; r < 16; ++r) {
        int idx2 = r * 1024 + t;         // 16384 = 256*64
        int d = idx2 >> 6, fc = idx2 & 63;
        int n = n0 + d;
        if (n < N) {
            float ox = bls[2 * fc], oy = bls[2 * fc + 1];
#pragma unroll
            for (int k = 0; k < 16; ++k) {
                float hv = accf[d * 20 + k];
                v2f wv = wl2[k * 64 + fc];
                ox += hv * wv.x;
                oy += hv * wv.y;
            }
            v2f o; o.x = ox; o.y = oy;
            __builtin_nontemporal_store(o, (v2f*)(out + (size_t)n * 128 + 2 * fc));
        }
    }
}

extern "C" void kernel_launch(void* const* d_in, const int* in_sizes, int n_in,
                              void* d_out, int out_size, void* d_ws, size_t ws_size,
                              hipStream_t stream) {
    const float* x  = (const float*)d_in[0];
    const int*   ei = (const int*)d_in[1];
    const float* W1 = (const float*)d_in[2];
    const float* b1 = (const float*)d_in[3];
    const float* W2 = (const float*)d_in[4];
    const float* b2 = (const float*)d_in[5];
    const float* Wl = (const float*)d_in[6];
    const float* bl = (const float*)d_in[7];
    float*       out = (float*)d_out;

    const int N = in_sizes[0] / 128;
    const int E = in_sizes[1] / 2;
    const int NB = (N + NPB - 1) >> NPB_SHIFT;   // buckets used (<= NB_MAX)

    char* ws = (char*)d_ws;
    auto carve = [&](size_t bytes) {
        char* p = ws;
        ws += (bytes + 255) & ~(size_t)255;
        return p;
    };
    int*    bucket_cnt  = (int*)carve((size_t)NB_MAX * 4);
    int*    bucket_base = (int*)carve((size_t)NB_MAX * 4);
    int*    bucket_cur  = (int*)carve((size_t)NB_MAX * 4);
    float*  dinv        = (float*)carve((size_t)N * 4);
    int*    pairs       = (int*)carve(((size_t)E + 16 * NB_MAX) * 4);
    int*    srcs        = (int*)carve(((size_t)E + 16 * NB_MAX) * 4);
    int*    nodeoff     = (int*)carve((size_t)N * 4);
    int*    degarr      = (int*)carve((size_t)N * 4);
    __half* g1          = (__half*)carve((size_t)N * 16 * 2);
    __half* g2          = (__half*)carve((size_t)N * 16 * 2);
    (void)ws_size; (void)n_in; (void)out_size;

    hipMemsetAsync(bucket_cnt, 0, (size_t)NB_MAX * 4, stream);
    k_bucket_cnt<<<512, 256, 0, stream>>>(ei, bucket_cnt, E);
    k_bucket_scan<<<1, NB_MAX, 0, stream>>>(bucket_cnt, bucket_base, bucket_cur);
    k_partition<<<(E + PART_TILE - 1) / PART_TILE, PART_THR, 0, stream>>>(ei, bucket_cur, pairs, E);
    k_sortd<<<NB, 1024, 0, stream>>>(pairs, bucket_cnt, bucket_base, srcs, nodeoff, degarr, dinv, N);
    k_xform1<<<(N + 15) / 16, 256, 0, stream>>>(x, W1, dinv, g1, N);
    k_aggr1r<<<NB, 1024, 0, stream>>>(g1, srcs, nodeoff, degarr, dinv, b1, W2, g2, N);
    k_aggr2r<<<NB, 1024, 0, stream>>>(g2, srcs, nodeoff, degarr, dinv, b2, Wl, bl, out, N);
}

// Round 3
// 276.690 us; speedup vs baseline: 1.0113x; 1.0113x over previous
//
#include <hip/hip_runtime.h>
#include <hip/hip_fp16.h>

// ---------------------------------------------------------------------------
// GCN forward: h1 = relu(GCNConv(x, W1, b1)); h2 = relu(GCNConv(h1, W2, b2));
// out = h2 @ W_lin + b_lin
// N=100000, E=3200000, F_in=128, H=16, F_out=128.
// edge_index arrives as int32 [2*E]: row 0 = src, row 1 = dst.
//
// R11 pipeline (memset + 7 kernels):
//   memset(bucket_cnt) -> bucket_cnt -> scan -> partition (packed pairs,
//   bucket-contiguous) -> sortd (per-bucket counting sort by dst-local:
//   srcs[] fully dst-sorted + nodeoff/deg/dinv) -> xform1 -> aggr1r -> aggr2r.
// R11 change: R10 post-mortem showed aggregation is latency*concurrency
// bound (0.10 lines/cy/CU at ~1 outstanding line per lane-slot; VALUBusy
// 23%, conflicts 0, L2-resident). The per-group edge loop is now a 2-stage
// software pipeline: uniform trip count K = ceil(wavemax(deg)/8) (no
// loop-condition dependence on loaded values), src indices prefetched 2
// iters ahead, gather k+1 issued before accumulate k. Each wave holds 2-3
// loads (~35-70 cache lines) in flight continuously. __launch_bounds__
// (1024,8) pins VGPR<=64 so 2 blocks/CU (32 waves) stay resident.
// ---------------------------------------------------------------------------

typedef int   v4i __attribute__((ext_vector_type(4)));
typedef float v4f __attribute__((ext_vector_type(4)));
typedef float v2f __attribute__((ext_vector_type(2)));

#define NPB        256    // nodes per bucket
#define NPB_SHIFT  8
#define NB_MAX     512    // max buckets
#define PART_TILE  8192   // edges per partition block
#define PART_THR   1024
#define PT_ITERS   (PART_TILE / 4 / PART_THR)   // = 2 quads/thread

// Per-block LDS histogram of dst>>8, int4 loads, flushed once per block.
__global__ __launch_bounds__(256) void k_bucket_cnt(const int* __restrict__ ei,
                                                    int* __restrict__ bucket_cnt, int E) {
    __shared__ int h[NB_MAX];
    int t = threadIdx.x;
    for (int j = t; j < NB_MAX; j += 256) h[j] = 0;
    __syncthreads();
    const v4i* d4 = (const v4i*)(ei + E);
    int EQ = E >> 2;
    for (int q = blockIdx.x * 256 + t; q < EQ; q += gridDim.x * 256) {
        v4i dd = __builtin_nontemporal_load(d4 + q);
        atomicAdd(&h[dd.x >> NPB_SHIFT], 1);
        atomicAdd(&h[dd.y >> NPB_SHIFT], 1);
        atomicAdd(&h[dd.z >> NPB_SHIFT], 1);
        atomicAdd(&h[dd.w >> NPB_SHIFT], 1);
    }
    if (blockIdx.x == 0) {
        for (int e = (EQ << 2) + t; e < E; e += 256)
            atomicAdd(&h[ei[E + e] >> NPB_SHIFT], 1);
    }
    __syncthreads();
    for (int j = t; j < NB_MAX; j += 256)
        if (h[j]) atomicAdd(&bucket_cnt[j], h[j]);
}

// Exclusive scan of padded counts (pad to 16 pairs: 64B-aligned regions).
__global__ __launch_bounds__(NB_MAX) void k_bucket_scan(const int* __restrict__ bucket_cnt,
                                                        int* __restrict__ bucket_base,
                                                        int* __restrict__ bucket_cur) {
    __shared__ int s[NB_MAX];
    int t = threadIdx.x;
    int padded = (bucket_cnt[t] + 15) & ~15;
    s[t] = padded;
    __syncthreads();
    for (int off = 1; off < NB_MAX; off <<= 1) {
        int v = (t >= off) ? s[t - off] : 0;
        __syncthreads();
        s[t] += v;
        __syncthreads();
    }
    int excl = s[t] - padded;
    bucket_base[t] = excl;
    bucket_cur[t]  = excl;
}

// Partition edges into bucket-contiguous packed (src<<8 | dstlocal) runs.
__global__ __launch_bounds__(PART_THR) void k_partition(const int* __restrict__ ei,
                                                        int* __restrict__ bucket_cur,
                                                        int* __restrict__ pairs, int E) {
    __shared__ int h[NB_MAX];    // pass1: local hist; pass2: local cursor
    __shared__ int rb[NB_MAX];   // run base (absolute) per bucket
    int t = threadIdx.x;
    const v4i* s4 = (const v4i*)ei;
    const v4i* d4 = (const v4i*)(ei + E);
    int EQ = E >> 2;
    int q0 = blockIdx.x * (PART_TILE / 4);
    bool last = (blockIdx.x == gridDim.x - 1);
    v4i dsave[PT_ITERS];

    for (int j = t; j < NB_MAX; j += PART_THR) h[j] = 0;
    __syncthreads();
#pragma unroll
    for (int it = 0; it < PT_ITERS; ++it) {
        int q = q0 + it * PART_THR + t;
        v4i dd;
        if (q < EQ) {
            dd = __builtin_nontemporal_load(d4 + q);
            atomicAdd(&h[dd.x >> NPB_SHIFT], 1);
            atomicAdd(&h[dd.y >> NPB_SHIFT], 1);
            atomicAdd(&h[dd.z >> NPB_SHIFT], 1);
            atomicAdd(&h[dd.w >> NPB_SHIFT], 1);
        }
        dsave[it] = dd;
    }
    if (last) {
        for (int e = (EQ << 2) + t; e < E; e += PART_THR)
            atomicAdd(&h[ei[E + e] >> NPB_SHIFT], 1);
    }
    __syncthreads();
    for (int j = t; j < NB_MAX; j += PART_THR) {
        int c = h[j];
        rb[j] = c ? atomicAdd(&bucket_cur[j], c) : 0;
        h[j] = 0;
    }
    __syncthreads();
#pragma unroll
    for (int it = 0; it < PT_ITERS; ++it) {
        int q = q0 + it * PART_THR + t;
        if (q < EQ) {
            v4i ss = __builtin_nontemporal_load(s4 + q);
            v4i dd = dsave[it];
#pragma unroll
            for (int k = 0; k < 4; ++k) {
                int s = ss[k], d = dd[k];
                int b = d >> NPB_SHIFT;
                int pos = rb[b] + atomicAdd(&h[b], 1);
                pairs[pos] = (s << NPB_SHIFT) | (d & (NPB - 1));
            }
        }
    }
    if (last) {
        for (int e = (EQ << 2) + t; e < E; e += PART_THR) {
            int s = ei[e], d = ei[E + e];
            int b = d >> NPB_SHIFT;
            int pos = rb[b] + atomicAdd(&h[b], 1);
            pairs[pos] = (s << NPB_SHIFT) | (d & (NPB - 1));
        }
    }
}

// Per-bucket counting sort by dst-local. Produces srcs[] (src ids grouped by
// dst, dense in [base, base+cnt)), nodeoff[n], degarr[n], dinv[n].
__global__ __launch_bounds__(1024) void k_sortd(const int* __restrict__ pairs,
                                                const int* __restrict__ bucket_cnt,
                                                const int* __restrict__ bucket_base,
                                                int* __restrict__ srcs,
                                                int* __restrict__ nodeoff,
                                                int* __restrict__ degarr,
                                                float* __restrict__ dinv, int N) {
    __shared__ int h[NPB];    // hist -> inclusive scan (in place)
    __shared__ int cur[NPB];  // scatter cursors (absolute)
    int t = threadIdx.x, b = blockIdx.x;
    int cnt  = bucket_cnt[b];
    int base = bucket_base[b];   // 16-aligned
    if (t < NPB) h[t] = 0;
    __syncthreads();
    const v4i* p4 = (const v4i*)(pairs + base);
    int cq = cnt >> 2;
    for (int q = t; q < cq; q += 1024) {
        v4i pp = p4[q];
        atomicAdd(&h[pp.x & (NPB - 1)], 1);
        atomicAdd(&h[pp.y & (NPB - 1)], 1);
        atomicAdd(&h[pp.z & (NPB - 1)], 1);
        atomicAdd(&h[pp.w & (NPB - 1)], 1);
    }
    for (int i = (cq << 2) + t; i < cnt; i += 1024)
        atomicAdd(&h[pairs[base + i] & (NPB - 1)], 1);
    __syncthreads();
    int mydeg = (t < NPB) ? h[t] : 0;
    // Hillis-Steele inclusive scan over h[0..255]
    for (int off = 1; off < NPB; off <<= 1) {
        int v = (t < NPB && t >= off) ? h[t - off] : 0;
        __syncthreads();
        if (t < NPB) h[t] += v;
        __syncthreads();
    }
    if (t < NPB) {
        int no = base + h[t] - mydeg;   // exclusive
        cur[t] = no;
        int n = (b << NPB_SHIFT) + t;
        if (n < N) {
            nodeoff[n] = no;
            degarr[n]  = mydeg;
            dinv[n]    = rsqrtf((float)(mydeg + 1));
        }
    }
    __syncthreads();
    for (int q = t; q < cq; q += 1024) {
        v4i pp = p4[q];
#pragma unroll
        for (int k = 0; k < 4; ++k) {
            int p = pp[k];
            int pos = atomicAdd(&cur[p & (NPB - 1)], 1);
            srcs[pos] = p >> NPB_SHIFT;
        }
    }
    for (int i = (cq << 2) + t; i < cnt; i += 1024) {
        int p = pairs[base + i];
        int pos = atomicAdd(&cur[p & (NPB - 1)], 1);
        srcs[pos] = p >> NPB_SHIFT;
    }
}

// g1[n,:] = fp16( (x[n,:] @ W1) * dinv[n] )   (128 -> 16), 16 nodes per block
__global__ __launch_bounds__(256) void k_xform1(const float* __restrict__ x,
                                                const float* __restrict__ W1,
                                                const float* __restrict__ dinv,
                                                __half* __restrict__ g, int N) {
    __shared__ float xs[16][132];
    __shared__ float ws[128 * 16];
    int t = threadIdx.x;
    int n0 = blockIdx.x * 16;
    const v4f* w4 = (const v4f*)W1;
    const v4f* x4 = (const v4f*)x;
    for (int idx = t; idx < 512; idx += 256) ((v4f*)ws)[idx] = w4[idx];
    for (int idx = t; idx < 512; idx += 256) {
        int r = idx >> 5, c4 = idx & 31;
        int n = n0 + r;
        v4f v = (n < N) ? x4[(size_t)n * 32 + c4] : (v4f)(0.f);
        *(v4f*)&xs[r][c4 * 4] = v;
    }
    __syncthreads();
    int node = t >> 4, f = t & 15;
    int n = n0 + node;
    if (n < N) {
        float sum = 0.f;
#pragma unroll
        for (int k = 0; k < 128; ++k) sum += xs[node][k] * ws[k * 16 + f];
        g[(size_t)n * 16 + f] = __float2half_rn(sum * dinv[n]);
    }
}

// ---- R11 pipelined register-reduction aggregation -------------------------
// Block = 256-node range, 16 waves. Wave handles 16 nodes (4 groups of 4).
// Per node: 16 lanes = 8 edge-slots x 2 half-rows (8 fp16 feats each).
// Per group: uniform trip count K (wave-max deg), src prefetch 2 deep,
// gather issued 1 iter ahead of its accumulate -> 2-3 loads in flight per
// lane continuously (vs 1 serialized chain in R10).

__device__ __forceinline__ void accum8(float* fa, v4i r) {
#pragma unroll
    for (int j = 0; j < 4; ++j) {
        float2 fv = __half22float2(((const __half2*)&r)[j]);
        fa[2 * j]     += fv.x;
        fa[2 * j + 1] += fv.y;
    }
}

// Gathers this lane's share of one node group into fa[8].
__device__ __forceinline__ void gather_group(const __half* __restrict__ g,
                                             const int* __restrict__ srcs,
                                             int off, int dg, int es, int fo,
                                             float* fa) {
    // wave-max of dg (dg varies only over lane bits 4-5 = sub)
    int dm = dg;
    dm = max(dm, __shfl_xor(dm, 16, 64));
    dm = max(dm, __shfl_xor(dm, 32, 64));
    int K = (dm + 7) >> 3;
    int c = es;
    int s0 = (c < dg) ? srcs[off + c] : -1;
    v4i r0;
    if (s0 >= 0) r0 = *(const v4i*)(g + (size_t)s0 * 16 + fo);
    int s1 = (c + 8 < dg) ? srcs[off + c + 8] : -1;
    for (int k = 0; k < K; ++k) {
        v4i r1;
        if (s1 >= 0) r1 = *(const v4i*)(g + (size_t)s1 * 16 + fo);
        int s2 = (c + 16 < dg) ? srcs[off + c + 16] : -1;
        if (s0 >= 0) accum8(fa, r0);
        s0 = s1; s1 = s2; r0 = r1; c += 8;
    }
}

// Layer-1: g2[n,:] = fp16( relu(dinv*(sum+self)+b1) @ W2 * dinv )
__global__ __launch_bounds__(1024, 8) void k_aggr1r(const __half* __restrict__ g1,
                                                 const int* __restrict__ srcs,
                                                 const int* __restrict__ nodeoff,
                                                 const int* __restrict__ degarr,
                                                 const float* __restrict__ dinv,
                                                 const float* __restrict__ b1,
                                                 const float* __restrict__ W2,
                                                 __half* __restrict__ g2, int N) {
    __shared__ float accf[NPB * 20];    // stride 20: b128-aligned, bank-clean
    __shared__ float w2s[256];
    __shared__ float b1s[16];
    int t = threadIdx.x, b = blockIdx.x;
    int n0 = b << NPB_SHIFT;
    if (t < 256) w2s[t] = W2[t];
    if (t < 16)  b1s[t] = b1[t];
    __syncthreads();
    int w = t >> 6, l = t & 63;
    int sub = l >> 4, es = (l >> 1) & 7, fo = (l & 1) << 3;
#pragma unroll
    for (int g = 0; g < 4; ++g) {
        int nl = w * 16 + g * 4 + sub;
        int n = n0 + nl;
        bool v = n < N;
        int off = v ? nodeoff[n] : 0;
        int dg  = v ? degarr[n]  : 0;
        float fa[8] = {0.f, 0.f, 0.f, 0.f, 0.f, 0.f, 0.f, 0.f};
        gather_group(g1, srcs, off, dg, es, fo, fa);
#pragma unroll
        for (int m = 2; m <= 8; m <<= 1) {
#pragma unroll
            for (int j = 0; j < 8; ++j) fa[j] += __shfl_xor(fa[j], m, 64);
        }
        if (es == 0 && v) {
            v4i sr = *(const v4i*)(g1 + (size_t)n * 16 + fo);
            float di = dinv[n];
            float2 s0 = __half22float2(((const __half2*)&sr)[0]);
            float2 s1 = __half22float2(((const __half2*)&sr)[1]);
            float2 s2 = __half22float2(((const __half2*)&sr)[2]);
            float2 s3 = __half22float2(((const __half2*)&sr)[3]);
            float h0 = fmaxf(di * (fa[0] + s0.x) + b1s[fo + 0], 0.f);
            float h1v= fmaxf(di * (fa[1] + s0.y) + b1s[fo + 1], 0.f);
            float h2 = fmaxf(di * (fa[2] + s1.x) + b1s[fo + 2], 0.f);
            float h3 = fmaxf(di * (fa[3] + s1.y) + b1s[fo + 3], 0.f);
            float h4 = fmaxf(di * (fa[4] + s2.x) + b1s[fo + 4], 0.f);
            float h5 = fmaxf(di * (fa[5] + s2.y) + b1s[fo + 5], 0.f);
            float h6 = fmaxf(di * (fa[6] + s3.x) + b1s[fo + 6], 0.f);
            float h7 = fmaxf(di * (fa[7] + s3.y) + b1s[fo + 7], 0.f);
            v4f lo = {h0, h1v, h2, h3};
            v4f hi = {h4, h5, h6, h7};
            *((v4f*)(accf + nl * 20 + fo))     = lo;
            *((v4f*)(accf + nl * 20 + fo + 4)) = hi;
        }
    }
    __syncthreads();
    // phase B: g2 = fp16((h1 @ W2) * dinv), 2048 half2 outputs
#pragma unroll
    for (int r = 0; r < 2; ++r) {
        int idx2 = r * 1024 + t;         // 2048 = 256*8
        int d = idx2 >> 3, ff = idx2 & 7;
        int n = n0 + d;
        if (n < N) {
            float sx = 0.f, sy = 0.f;
#pragma unroll
            for (int k = 0; k < 16; ++k) {
                float hv = accf[d * 20 + k];
                sx += hv * w2s[k * 16 + 2 * ff];
                sy += hv * w2s[k * 16 + 2 * ff + 1];
            }
            float di = dinv[n];
            *(__half2*)(g2 + (size_t)n * 16 + 2 * ff) = __floats2half2_rn(sx * di, sy * di);
        }
    }
}

// Layer-2: out[n,:] = relu(dinv*(sum+self)+b2) @ W_lin + b_lin
__global__ __launch_bounds__(1024, 8) void k_aggr2r(const __half* __restrict__ g2,
                                                 const int* __restrict__ srcs,
                                                 const int* __restrict__ nodeoff,
                                                 const int* __restrict__ degarr,
                                                 const float* __restrict__ dinv,
                                                 const float* __restrict__ b2,
                                                 const float* __restrict__ Wl,
                                                 const float* __restrict__ bl,
                                                 float* __restrict__ out, int N) {
    __shared__ float accf[NPB * 20];
    __shared__ float wls[16 * 128];
    __shared__ float bls[128];
    __shared__ float b2s[16];
    int t = threadIdx.x, b = blockIdx.x;
    int n0 = b << NPB_SHIFT;
    if (t < 512) ((v4f*)wls)[t] = ((const v4f*)Wl)[t];
    if (t < 128) bls[t] = bl[t];
    if (t < 16)  b2s[t] = b2[t];
    __syncthreads();
    int w = t >> 6, l = t & 63;
    int sub = l >> 4, es = (l >> 1) & 7, fo = (l & 1) << 3;
#pragma unroll
    for (int g = 0; g < 4; ++g) {
        int nl = w * 16 + g * 4 + sub;
        int n = n0 + nl;
        bool v = n < N;
        int off = v ? nodeoff[n] : 0;
        int dg  = v ? degarr[n]  : 0;
        float fa[8] = {0.f, 0.f, 0.f, 0.f, 0.f, 0.f, 0.f, 0.f};
        gather_group(g2, srcs, off, dg, es, fo, fa);
#pragma unroll
        for (int m = 2; m <= 8; m <<= 1) {
#pragma unroll
            for (int j = 0; j < 8; ++j) fa[j] += __shfl_xor(fa[j], m, 64);
        }
        if (es == 0 && v) {
            v4i sr = *(const v4i*)(g2 + (size_t)n * 16 + fo);
            float di = dinv[n];
            float2 s0 = __half22float2(((const __half2*)&sr)[0]);
            float2 s1 = __half22float2(((const __half2*)&sr)[1]);
            float2 s2 = __half22float2(((const __half2*)&sr)[2]);
            float2 s3 = __half22float2(((const __half2*)&sr)[3]);
            float h0 = fmaxf(di * (fa[0] + s0.x) + b2s[fo + 0], 0.f);
            float h1v= fmaxf(di * (fa[1] + s0.y) + b2s[fo + 1], 0.f);
            float h2 = fmaxf(di * (fa[2] + s1.x) + b2s[fo + 2], 0.f);
            float h3 = fmaxf(di * (fa[3] + s1.y) + b2s[fo + 3], 0.f);
            float h4 = fmaxf(di * (fa[4] + s2.x) + b2s[fo + 4], 0.f);
            float h5 = fmaxf(di * (fa[5] + s2.y) + b2s[fo + 5], 0.f);
            float h6 = fmaxf(di * (fa[6] + s3.x) + b2s[fo + 6], 0.f);
            float h7 = fmaxf(di * (fa[7] + s3.y) + b2s[fo + 7], 0.f);
            v4f lo = {h0, h1v, h2, h3};
            v4f hi = {h4, h5, h6, h7};
            *((v4f*)(accf + nl * 20 + fo))     = lo;
            *((v4f*)(accf + nl * 20 + fo + 4)) = hi;
        }
    }
    __syncthreads();
    // phase B: out = h2 @ W_lin + b_lin; 16384 float2 outputs, coalesced
    const v2f* wl2 = (const v2f*)wls;
#pragma unroll
    for (int r = 0; r < 16; ++r) {
        int idx2 = r * 1024 + t;         // 16384 = 256*64
        int d = idx2 >> 6, fc = idx2 & 63;
        int n = n0 + d;
        if (n < N) {
            float ox = bls[2 * fc], oy = bls[2 * fc + 1];
#pragma unroll
            for (int k = 0; k < 16; ++k) {
                float hv = accf[d * 20 + k];
                v2f wv = wl2[k * 64 + fc];
                ox += hv * wv.x;
                oy += hv * wv.y;
            }
            v2f o; o.x = ox; o.y = oy;
            __builtin_nontemporal_store(o, (v2f*)(out + (size_t)n * 128 + 2 * fc));
        }
    }
}

extern "C" void kernel_launch(void* const* d_in, const int* in_sizes, int n_in,
                              void* d_out, int out_size, void* d_ws, size_t ws_size,
                              hipStream_t stream) {
    const float* x  = (const float*)d_in[0];
    const int*   ei = (const int*)d_in[1];
    const float* W1 = (const float*)d_in[2];
    const float* b1 = (const float*)d_in[3];
    const float* W2 = (const float*)d_in[4];
    const float* b2 = (const float*)d_in[5];
    const float* Wl = (const float*)d_in[6];
    const float* bl = (const float*)d_in[7];
    float*       out = (float*)d_out;

    const int N = in_sizes[0] / 128;
    const int E = in_sizes[1] / 2;
    const int NB = (N + NPB - 1) >> NPB_SHIFT;   // buckets used (<= NB_MAX)

    char* ws = (char*)d_ws;
    auto carve = [&](size_t bytes) {
        char* p = ws;
        ws += (bytes + 255) & ~(size_t)255;
        return p;
    };
    int*    bucket_cnt  = (int*)carve((size_t)NB_MAX * 4);
    int*    bucket_base = (int*)carve((size_t)NB_MAX * 4);
    int*    bucket_cur  = (int*)carve((size_t)NB_MAX * 4);
    float*  dinv        = (float*)carve((size_t)N * 4);
    int*    pairs       = (int*)carve(((size_t)E + 16 * NB_MAX) * 4);
    int*    srcs        = (int*)carve(((size_t)E + 16 * NB_MAX) * 4);
    int*    nodeoff     = (int*)carve((size_t)N * 4);
    int*    degarr      = (int*)carve((size_t)N * 4);
    __half* g1          = (__half*)carve((size_t)N * 16 * 2);
    __half* g2          = (__half*)carve((size_t)N * 16 * 2);
    (void)ws_size; (void)n_in; (void)out_size;

    hipMemsetAsync(bucket_cnt, 0, (size_t)NB_MAX * 4, stream);
    k_bucket_cnt<<<512, 256, 0, stream>>>(ei, bucket_cnt, E);
    k_bucket_scan<<<1, NB_MAX, 0, stream>>>(bucket_cnt, bucket_base, bucket_cur);
    k_partition<<<(E + PART_TILE - 1) / PART_TILE, PART_THR, 0, stream>>>(ei, bucket_cur, pairs, E);
    k_sortd<<<NB, 1024, 0, stream>>>(pairs, bucket_cnt, bucket_base, srcs, nodeoff, degarr, dinv, N);
    k_xform1<<<(N + 15) / 16, 256, 0, stream>>>(x, W1, dinv, g1, N);
    k_aggr1r<<<NB, 1024, 0, stream>>>(g1, srcs, nodeoff, degarr, dinv, b1, W2, g2, N);
    k_aggr2r<<<NB, 1024, 0, stream>>>(g2, srcs, nodeoff, degarr, dinv, b2, Wl, bl, out, N);
}